// Round 7
// baseline (60.617 us; speedup 1.0000x reference)
//
#include <hip/hip_runtime.h>
#include <hip/hip_bf16.h>

#define H_IMG 720
#define W_IMG 1280
#define NPIX (H_IMG * W_IMG)

typedef __attribute__((ext_vector_type(4))) float f32x4;
typedef __attribute__((ext_vector_type(8))) short short8;
typedef __attribute__((ext_vector_type(4))) short short4v;

// ---- workspace layout (bytes) ----
// wpack: 14 hi-frags * 64 lanes * 16B
#define WPACK_BYTES (14 * 64 * 16)
#define GP0_OFF WPACK_BYTES
#define GP0_N (16 * 16 * 8 * 8)   // [y][x][z][c] f32
#define GP1_OFF (GP0_OFF + GP0_N * 4)
#define GP1_N (12 * 12 * 8 * 8)
#define GP2_OFF (GP1_OFF + GP1_N * 4)
#define GP2_N (8 * 8 * 4 * 8)

#define XSTR 36  // ushorts per staging row: 32 payload + 4 pad

__device__ __forceinline__ uint pkbf(float a, float b) {
  // packed f32x2 -> bf16x2 (v_cvt_pk_bf16_f32), RNE
  float2 t2 = make_float2(a, b);
  __hip_bfloat162 t = __float22bfloat162_rn(t2);
  uint u;
  __builtin_memcpy(&u, &t, 4);
  return u;
}

__device__ __forceinline__ float tanh5(float x) {
  // tanh(x) = 1 - 2/(e^{2x}+1); graceful at +-inf, no clamp needed.
  float e2 = __builtin_amdgcn_exp2f(x * 2.885390081777927f);  // e^{2x} via v_exp_f32
  return fmaf(-2.f, __builtin_amdgcn_rcpf(e2 + 1.f), 1.f);
}

// ================= prep kernel =================
__global__ __launch_bounds__(256) void prep_kernel(
    const float* __restrict__ g0, const float* __restrict__ g1, const float* __restrict__ g2,
    const float* __restrict__ w1, const float* __restrict__ w2, const float* __restrict__ w3,
    const int* __restrict__ cam, void* __restrict__ ws) {
  ushort* wpack = (ushort*)ws;
  float* gp0 = (float*)((char*)ws + GP0_OFF);
  float* gp1 = (float*)((char*)ws + GP1_OFF);
  float* gp2 = (float*)((char*)ws + GP2_OFF);
  const int ci = cam[0];
  const int tid = blockIdx.x * 256 + threadIdx.x;
  const int nth = gridDim.x * 256;

  // grids -> [y][x][z][c] f32, selected view only
  for (int e = tid; e < GP0_N; e += nth) {
    int c = e & 7; int t = e >> 3; int z = t & 7; t >>= 3; int x = t & 15; int y = t >> 4;
    gp0[e] = g0[ci * GP0_N + ((c * 8 + z) * 16 + y) * 16 + x];
  }
  for (int e = tid; e < GP1_N; e += nth) {
    int c = e & 7; int t = e >> 3; int z = t & 7; t >>= 3; int x = t % 12; int y = t / 12;
    gp1[e] = g1[ci * GP1_N + ((c * 8 + z) * 12 + y) * 12 + x];
  }
  for (int e = tid; e < GP2_N; e += nth) {
    int c = e & 7; int t = e >> 3; int z = t & 3; t >>= 2; int x = t & 7; int y = t >> 3;
    gp2[e] = g2[ci * GP2_N + ((c * 4 + z) * 8 + y) * 8 + x];
  }

  // weights -> per-lane A-fragments (A = W^T), hi bf16 only.
  // frag f: 0..3 = L1 (mt), 4..11 = L2 (4+ks*4+mt), 12..13 = L3 (ks).
  for (int fl = tid; fl < 14 * 64; fl += nth) {
    int f = fl >> 6, lane = fl & 63;
    int g = lane >> 4, r = lane & 15;
    ushort* dh = wpack + fl * 8;
#pragma unroll
    for (int j = 0; j < 8; ++j) {
      float v = 0.f;
      if (f < 4) {
        int k = 8 * g + j, n = r + 16 * f;
        if (k < 24) v = w1[k * 64 + n];
      } else if (f < 12) {
        int q = f - 4, ks = q >> 2, mt = q & 3;
        v = w2[(8 * g + j + 32 * ks) * 64 + (r + 16 * mt)];
      } else {
        int ks = f - 12;
        if (r < 12) v = w3[(8 * g + j + 32 * ks) * 12 + r];
      }
      __hip_bfloat16 bh = __float2bfloat16(v);
      dh[j] = *(ushort*)&bh;
    }
  }
}

// ================= slicing =================
template <int WG, int HG, int LG>
__device__ __forceinline__ void slice_pack(const float* __restrict__ gp,
                                           int row, int col, float gray,
                                           float* __restrict__ out8) {
  float x = (float)col * ((float)(WG - 1) / (float)(W_IMG - 1));
  float y = (float)row * ((float)(HG - 1) / (float)(H_IMG - 1));
  float z = gray * (float)(LG - 1);
  int x0 = (int)x, y0 = (int)y, z0 = (int)z;
  int x1 = min(x0 + 1, WG - 1), y1 = min(y0 + 1, HG - 1), z1 = min(z0 + 1, LG - 1);
  float wx = x - (float)x0, wy = y - (float)y0, wz = z - (float)z0;

  const float* p00 = gp + ((y0 * WG + x0) * LG) * 8;
  const float* p01 = gp + ((y0 * WG + x1) * LG) * 8;
  const float* p10 = gp + ((y1 * WG + x0) * LG) * 8;
  const float* p11 = gp + ((y1 * WG + x1) * LG) * 8;

  f32x4 s00a = *(const f32x4*)(p00 + z0 * 8), s00b = *(const f32x4*)(p00 + z0 * 8 + 4);
  f32x4 s01a = *(const f32x4*)(p01 + z0 * 8), s01b = *(const f32x4*)(p01 + z0 * 8 + 4);
  f32x4 s10a = *(const f32x4*)(p10 + z0 * 8), s10b = *(const f32x4*)(p10 + z0 * 8 + 4);
  f32x4 s11a = *(const f32x4*)(p11 + z0 * 8), s11b = *(const f32x4*)(p11 + z0 * 8 + 4);
  f32x4 t00a = *(const f32x4*)(p00 + z1 * 8), t00b = *(const f32x4*)(p00 + z1 * 8 + 4);
  f32x4 t01a = *(const f32x4*)(p01 + z1 * 8), t01b = *(const f32x4*)(p01 + z1 * 8 + 4);
  f32x4 t10a = *(const f32x4*)(p10 + z1 * 8), t10b = *(const f32x4*)(p10 + z1 * 8 + 4);
  f32x4 t11a = *(const f32x4*)(p11 + z1 * 8), t11b = *(const f32x4*)(p11 + z1 * 8 + 4);

#pragma unroll
  for (int c = 0; c < 8; ++c) {
    float c00 = (c < 4) ? s00a[c & 3] : s00b[c & 3];
    float c01 = (c < 4) ? s01a[c & 3] : s01b[c & 3];
    float c10 = (c < 4) ? s10a[c & 3] : s10b[c & 3];
    float c11 = (c < 4) ? s11a[c & 3] : s11b[c & 3];
    float d00 = (c < 4) ? t00a[c & 3] : t00b[c & 3];
    float d01 = (c < 4) ? t01a[c & 3] : t01b[c & 3];
    float d10 = (c < 4) ? t10a[c & 3] : t10b[c & 3];
    float d11 = (c < 4) ? t11a[c & 3] : t11b[c & 3];
    float h0 = fmaf(wx, c01 - c00, c00);
    float h1 = fmaf(wx, c11 - c10, c10);
    float v0 = fmaf(wy, h1 - h0, h0);
    float g0v = fmaf(wx, d01 - d00, d00);
    float g1v = fmaf(wx, d11 - d10, d10);
    float v1 = fmaf(wy, g1v - g0v, g0v);
    out8[c] = fmaf(wz, v1 - v0, v0);
  }
}

// ================= main kernel =================
// One reused 64x36-ushort staging region per wave: X -> H1a -> H1b -> H2a -> H2b.
// All DS traffic is wave-private and in-order; no barriers anywhere.
// launch_bounds(256,4): VGPR cap 128. All 14 A-frags prefetched at entry
// (56 VGPR) so their L2 latency hides under the slicing phase.
__global__ __launch_bounds__(256, 4) void msnbat_kernel(
    const float* __restrict__ rgb, const void* __restrict__ ws, float* __restrict__ out) {
  __shared__ ushort LDS[4][64 * XSTR];  // 18432 B/block

  const short8* wp = (const short8*)ws;  // frag f, lane l -> wp[f*64+l]
  const float* gp0 = (const float*)((const char*)ws + GP0_OFF);
  const float* gp1 = (const float*)((const char*)ws + GP1_OFF);
  const float* gp2 = (const float*)((const char*)ws + GP2_OFF);

  const int wave = threadIdx.x >> 6, lane = threadIdx.x & 63;
  const int g = lane >> 4, r = lane & 15;
  ushort* W = LDS[wave];
  uint* Wu = (uint*)W;
  const int pixbase = blockIdx.x * 256 + wave * 64;
  const int p = pixbase + lane;
  const int row = p / W_IMG;
  const int col = p - row * W_IMG;

  // ---- prefetch all 14 A-fragments (issued before slicing; latency hidden) ----
  short8 Afr[14];
#pragma unroll
  for (int fi = 0; fi < 14; ++fi) Afr[fi] = wp[fi * 64 + lane];

  const float rr = rgb[p * 3 + 0], gg = rgb[p * 3 + 1], bb = rgb[p * 3 + 2];
  const float gray = fminf(fmaxf(rr * 0.299f + gg * 0.587f + bb * 0.114f, 0.f), 1.f);

  // ---- slice 24 features (lane = its own pixel) ----
  float f[24];
  slice_pack<16, 16, 8>(gp0, row, col, gray, f);
  slice_pack<12, 12, 8>(gp1, row, col, gray, f + 8);
  slice_pack<8, 8, 4>(gp2, row, col, gray, f + 16);

  // ---- stage X: row = pixel(lane), cols 0..23 bf16 feats (24..31 unwritten) ----
  {
    const int ub = lane * 18;  // uint base of this row
#pragma unroll
    for (int i = 0; i < 6; ++i) {
      uint2 v = make_uint2(pkbf(f[4 * i + 0], f[4 * i + 1]), pkbf(f[4 * i + 2], f[4 * i + 3]));
      *(uint2*)&Wu[ub + 2 * i] = v;
    }
  }

  const short8 zero8 = (short8){0, 0, 0, 0, 0, 0, 0, 0};

  // ---- B1 frags: lane(g,r) reads X[pixel r+16nt][feat 8g+j]; g==3 = K-pad -> 0 ----
  short8 B1[4];
#pragma unroll
  for (int nt = 0; nt < 4; ++nt) {
    short4v lo = *(short4v*)&W[(r + 16 * nt) * XSTR + 8 * g];
    short4v hi = *(short4v*)&W[(r + 16 * nt) * XSTR + 8 * g + 4];
    short8 v = __builtin_shufflevector(lo, hi, 0, 1, 2, 3, 4, 5, 6, 7);
    B1[nt] = (g < 3) ? v : zero8;
  }

  // ---- L1 (24->64) in mt-halves; stage tanh(H1) halves; build B2 frags ----
  short8 B2[2][4];
#pragma unroll
  for (int half = 0; half < 2; ++half) {
#pragma unroll
    for (int mtl = 0; mtl < 2; ++mtl) {
      const int mt = 2 * half + mtl;
      f32x4 a[4];
#pragma unroll
      for (int nt = 0; nt < 4; ++nt) a[nt] = (f32x4){0.f, 0.f, 0.f, 0.f};
#pragma unroll
      for (int nt = 0; nt < 4; ++nt)
        a[nt] = __builtin_amdgcn_mfma_f32_16x16x32_bf16(Afr[mt], B1[nt], a[nt], 0, 0, 0);
#pragma unroll
      for (int nt = 0; nt < 4; ++nt) {
        uint2 v = make_uint2(pkbf(tanh5(a[nt][0]), tanh5(a[nt][1])),
                             pkbf(tanh5(a[nt][2]), tanh5(a[nt][3])));
        *(uint2*)&Wu[(16 * nt + r) * 18 + 8 * mtl + 2 * g] = v;
      }
    }
#pragma unroll
    for (int nt = 0; nt < 4; ++nt) {
      short4v lo = *(short4v*)&W[(16 * nt + r) * XSTR + 8 * g];
      short4v hi = *(short4v*)&W[(16 * nt + r) * XSTR + 8 * g + 4];
      B2[half][nt] = __builtin_shufflevector(lo, hi, 0, 1, 2, 3, 4, 5, 6, 7);
    }
  }

  // ---- L2 (64->64) in mt-halves; stage tanh(H2) halves; build B3 frags ----
  short8 B3[2][4];
#pragma unroll
  for (int half = 0; half < 2; ++half) {
#pragma unroll
    for (int mtl = 0; mtl < 2; ++mtl) {
      const int mt = 2 * half + mtl;
      f32x4 a[4];
#pragma unroll
      for (int nt = 0; nt < 4; ++nt) a[nt] = (f32x4){0.f, 0.f, 0.f, 0.f};
#pragma unroll
      for (int nt = 0; nt < 4; ++nt)
        a[nt] = __builtin_amdgcn_mfma_f32_16x16x32_bf16(Afr[4 + mt], B2[0][nt], a[nt], 0, 0, 0);
#pragma unroll
      for (int nt = 0; nt < 4; ++nt)
        a[nt] = __builtin_amdgcn_mfma_f32_16x16x32_bf16(Afr[8 + mt], B2[1][nt], a[nt], 0, 0, 0);
#pragma unroll
      for (int nt = 0; nt < 4; ++nt) {
        uint2 v = make_uint2(pkbf(tanh5(a[nt][0]), tanh5(a[nt][1])),
                             pkbf(tanh5(a[nt][2]), tanh5(a[nt][3])));
        *(uint2*)&Wu[(16 * nt + r) * 18 + 8 * mtl + 2 * g] = v;
      }
    }
#pragma unroll
    for (int nt = 0; nt < 4; ++nt) {
      short4v lo = *(short4v*)&W[(16 * nt + r) * XSTR + 8 * g];
      short4v hi = *(short4v*)&W[(16 * nt + r) * XSTR + 8 * g + 4];
      B3[half][nt] = __builtin_shufflevector(lo, hi, 0, 1, 2, 3, 4, 5, 6, 7);
    }
  }

  // ---- L3 (64->12): M=16 (12 valid), K=64 ----
  f32x4 acc3[4];
#pragma unroll
  for (int nt = 0; nt < 4; ++nt) acc3[nt] = (f32x4){0.f, 0.f, 0.f, 0.f};
#pragma unroll
  for (int nt = 0; nt < 4; ++nt)
    acc3[nt] = __builtin_amdgcn_mfma_f32_16x16x32_bf16(Afr[12], B3[0][nt], acc3[nt], 0, 0, 0);
#pragma unroll
  for (int nt = 0; nt < 4; ++nt)
    acc3[nt] = __builtin_amdgcn_mfma_f32_16x16x32_bf16(Afr[13], B3[1][nt], acc3[nt], 0, 0, 0);

  // ---- store: lane(g<3, r) holds channels 4g..4g+3 of pixel 16nt+r ----
  if (g < 3) {
#pragma unroll
    for (int nt = 0; nt < 4; ++nt) {
      int pix = pixbase + 16 * nt + r;
      *(f32x4*)(out + pix * 12 + 4 * g) = acc3[nt];
    }
  }
}

extern "C" void kernel_launch(void* const* d_in, const int* in_sizes, int n_in,
                              void* d_out, int out_size, void* d_ws, size_t ws_size,
                              hipStream_t stream) {
  const float* rgb = (const float*)d_in[0];
  const float* g0 = (const float*)d_in[1];
  const float* g1 = (const float*)d_in[2];
  const float* g2 = (const float*)d_in[3];
  const float* w1 = (const float*)d_in[4];
  const float* w2 = (const float*)d_in[5];
  const float* w3 = (const float*)d_in[6];
  const int* cam = (const int*)d_in[7];
  float* out = (float*)d_out;

  hipLaunchKernelGGL(prep_kernel, dim3(64), dim3(256), 0, stream,
                     g0, g1, g2, w1, w2, w3, cam, d_ws);
  hipLaunchKernelGGL(msnbat_kernel, dim3(NPIX / 256), dim3(256), 0, stream,
                     rgb, d_ws, out);
}